// Round 6
// baseline (799.488 us; speedup 1.0000x reference)
//
#include <hip/hip_runtime.h>

// Problem constants (from reference)
#define N_NODES 2048
#define C_CH    128
#define NIRR    9
#define E_EL    10
// dslot mapping: 0 -> l0 (d=0), 1..3 -> l1 (d=0..2)

// Symmetrized coupling tables (tiny, wave-uniform, scalar-loaded):
//   us3: [s3(165 triples p<=q<=i)][16 = ds*4+k]
//   us2: [s2(45 pairs p<=q)][12 = ds*3+k]
//   us1: [p(9)][8 = ds*2+k]
#define NS3 165
#define NS2 45
#define US3_FLOATS (NS3 * 16)   // 2640
#define US2_FLOATS (NS2 * 12)   //  540
#define US1_FLOATS (9 * 8)      //   72

// Symmetrize u3/u2/u1 over index-permutation orbits (monomial x_p x_q x_i is
// symmetric, so only sorted index tuples matter). Output is 3252 floats total.
__global__ __launch_bounds__(256) void build_sym_kernel(
    const float* __restrict__ u3_l0, const float* __restrict__ u2_l0, const float* __restrict__ u1_l0,
    const float* __restrict__ u3_l1, const float* __restrict__ u2_l1, const float* __restrict__ u1_l1,
    float* __restrict__ us3, float* __restrict__ us2, float* __restrict__ us1)
{
    int t = blockIdx.x * 256 + threadIdx.x;
    if (t < US3_FLOATS) {
        int s = t >> 4, dk = t & 15, ds = dk >> 2, k = dk & 3;
        int pp = 0, qq = 0, ii = 0, cntr = 0;
        for (int p = 0; p < 9; p++)
            for (int q = p; q < 9; q++)
                for (int i = q; i < 9; i++) {
                    if (cntr == s) { pp = p; qq = q; ii = i; }
                    cntr++;
                }
        const float* u = (ds == 0) ? u3_l0 : (u3_l1 + (ds - 1) * 2916);
        int perm[6][3] = {{pp,qq,ii},{pp,ii,qq},{qq,pp,ii},{qq,ii,pp},{ii,pp,qq},{ii,qq,pp}};
        float acc = 0.f;
        #pragma unroll
        for (int j = 0; j < 6; j++)
            acc += u[((perm[j][0] * 9 + perm[j][1]) * 9 + perm[j][2]) * 4 + k];
        float mult = (pp == qq && qq == ii) ? 6.f : ((pp == qq || qq == ii) ? 2.f : 1.f);
        us3[t] = acc / mult;
    } else if (t < US3_FLOATS + US2_FLOATS) {
        int t2 = t - US3_FLOATS;
        int s = t2 / 12, dk = t2 % 12, ds = dk / 3, k = dk % 3;
        int pp = 0, qq = 0, cntr = 0;
        for (int p = 0; p < 9; p++)
            for (int q = p; q < 9; q++) {
                if (cntr == s) { pp = p; qq = q; }
                cntr++;
            }
        const float* u = (ds == 0) ? u2_l0 : (u2_l1 + (ds - 1) * 243);
        float acc = u[(pp * 9 + qq) * 3 + k] + u[(qq * 9 + pp) * 3 + k];
        us2[t2] = (pp == qq) ? acc * 0.5f : acc;
    } else if (t < US3_FLOATS + US2_FLOATS + US1_FLOATS) {
        int t1 = t - US3_FLOATS - US2_FLOATS;
        int p = t1 >> 3, dk = t1 & 7, ds = dk >> 1, k = dk & 1;
        const float* u = (ds == 0) ? u1_l0 : (u1_l1 + (ds - 1) * 18);
        us1[t1] = u[p * 2 + k];
    }
}

// Main contraction. grid = 1024 blocks exactly (every block works).
// Block = 2 nodes x 128 c; 1 node/thread; element id computed inline from
// the one-hot (wave-uniform address -> L1 broadcast). Table entries are
// wave-uniform with compile-time offsets -> scalar s_load into SGPRs; each
// FMA is v_fmac vG, sU, vX (no VGPR pressure from the table).
__global__ __launch_bounds__(256, 8) void contract_kernel(
    const float* __restrict__ x, const float* __restrict__ y,
    const float* __restrict__ us3, const float* __restrict__ us2, const float* __restrict__ us1,
    const float* __restrict__ w3_l0, const float* __restrict__ w2_l0, const float* __restrict__ w1_l0,
    const float* __restrict__ w3_l1, const float* __restrict__ w2_l1, const float* __restrict__ w1_l1,
    float4* __restrict__ fbuf)
{
    int tid = threadIdx.x;
    int c = tid & 127;
    int sub = tid >> 7;
    int b = blockIdx.x * 2 + sub;

    int e = 0;
    #pragma unroll
    for (int k = 1; k < E_EL; k++)
        if (y[b * E_EL + k] > 0.5f) e = k;

    float xv[9];
    {
        const float* xp = x + ((size_t)b * C_CH + c) * NIRR;
        #pragma unroll
        for (int i = 0; i < 9; i++) xv[i] = xp[i];
    }

    float G3[16], G2[12], G1[8];
    #pragma unroll
    for (int t = 0; t < 16; t++) G3[t] = 0.f;
    #pragma unroll
    for (int t = 0; t < 12; t++) G2[t] = 0.f;
    #pragma unroll
    for (int t = 0; t < 8; t++) G1[t] = 0.f;

    int s3 = 0, s2 = 0;
    #pragma unroll
    for (int p = 0; p < 9; p++) {
        float xp = xv[p];
        #pragma unroll
        for (int k = 0; k < 8; k++) G1[k] += us1[p * 8 + k] * xp;
        #pragma unroll
        for (int q = p; q < 9; q++) {
            float pq = xp * xv[q];
            #pragma unroll
            for (int k = 0; k < 12; k++) G2[k] += us2[s2 * 12 + k] * pq;
            s2++;
            #pragma unroll
            for (int i = q; i < 9; i++) {
                float X = pq * xv[i];
                #pragma unroll
                for (int k = 0; k < 16; k++) G3[k] += us3[s3 * 16 + k] * X;
                s3++;
            }
        }
    }

    // element weights (lane c): w3 (E,4,C), w2 (E,3,C), w1 (E,2,C)
    float f[4];
    {
        float acc = 0.f;
        #pragma unroll
        for (int k = 0; k < 4; k++) acc += w3_l0[(e * 4 + k) * 128 + c] * G3[k];
        #pragma unroll
        for (int k = 0; k < 3; k++) acc += w2_l0[(e * 3 + k) * 128 + c] * G2[k];
        #pragma unroll
        for (int k = 0; k < 2; k++) acc += w1_l0[(e * 2 + k) * 128 + c] * G1[k];
        f[0] = acc;
    }
    float w31[4], w21[3], w11[2];
    #pragma unroll
    for (int k = 0; k < 4; k++) w31[k] = w3_l1[(e * 4 + k) * 128 + c];
    #pragma unroll
    for (int k = 0; k < 3; k++) w21[k] = w2_l1[(e * 3 + k) * 128 + c];
    #pragma unroll
    for (int k = 0; k < 2; k++) w11[k] = w1_l1[(e * 2 + k) * 128 + c];
    #pragma unroll
    for (int ds = 1; ds < 4; ds++) {
        float acc = 0.f;
        #pragma unroll
        for (int k = 0; k < 4; k++) acc += w31[k] * G3[ds * 4 + k];
        #pragma unroll
        for (int k = 0; k < 3; k++) acc += w21[k] * G2[ds * 3 + k];
        #pragma unroll
        for (int k = 0; k < 2; k++) acc += w11[k] * G1[ds * 2 + k];
        f[ds] = acc;
    }
    // [node][c][m] layout, one coalesced 16B store
    fbuf[(size_t)b * C_CH + c] = make_float4(f[0], f[1], f[2], f[3]);
}

// o3.Linear + skip. Block = 8 nodes x 32 j-blocks (J=4 columns/thread).
// fs staged as float4[nb][129] (padded): one ds_read_b128 yields all 4
// dslot values for (nb,i) -> 16 FMA per LDS read. w read as coalesced
// float4 from global (L2-hot, 128 KB shared by all blocks).
__global__ __launch_bounds__(256) void linear_kernel(
    const float4* __restrict__ fbuf,
    const float* __restrict__ lw0, const float* __restrict__ lw1,
    const float* __restrict__ sc, float* __restrict__ out)
{
    __shared__ float4 fs[8][129];  // padded to break bank alignment
    int b0 = blockIdx.x * 8;
    int tid = threadIdx.x;
    for (int t = tid; t < 1024; t += 256) {
        int nb = t >> 7, i = t & 127;
        fs[nb][i] = fbuf[(size_t)(b0 + nb) * C_CH + i];
    }
    __syncthreads();

    int jb = tid & 31;      // 32 j-blocks of 4 columns
    int nb = tid >> 5;      // 8 nodes
    const float4* w0v4 = (const float4*)lw0;
    const float4* w1v4 = (const float4*)lw1;

    float a0[4] = {0,0,0,0}, a1[4] = {0,0,0,0}, a2[4] = {0,0,0,0}, a3[4] = {0,0,0,0};
    for (int i = 0; i < 128; i++) {
        float4 fv = fs[nb][i];
        float4 w0 = w0v4[i * 32 + jb];
        float4 w1 = w1v4[i * 32 + jb];
        a0[0] += fv.x * w0.x; a0[1] += fv.x * w0.y; a0[2] += fv.x * w0.z; a0[3] += fv.x * w0.w;
        a1[0] += fv.y * w1.x; a1[1] += fv.y * w1.y; a1[2] += fv.y * w1.z; a1[3] += fv.y * w1.w;
        a2[0] += fv.z * w1.x; a2[1] += fv.z * w1.y; a2[2] += fv.z * w1.z; a2[3] += fv.z * w1.w;
        a3[0] += fv.w * w1.x; a3[1] += fv.w * w1.y; a3[2] += fv.w * w1.z; a3[3] += fv.w * w1.w;
    }

    const float inv_sqrt_c = 0.08838834764831845f;  // 1/sqrt(128)
    size_t ob = (size_t)(b0 + nb) * 512;
    int j0 = jb * 4;
    #pragma unroll
    for (int jj = 0; jj < 4; jj++)
        out[ob + j0 + jj] = a0[jj] * inv_sqrt_c + sc[ob + j0 + jj];
    int col = 128 + 3 * j0;
    #pragma unroll
    for (int jj = 0; jj < 4; jj++) {
        out[ob + col + 3 * jj + 0] = a1[jj] * inv_sqrt_c + sc[ob + col + 3 * jj + 0];
        out[ob + col + 3 * jj + 1] = a2[jj] * inv_sqrt_c + sc[ob + col + 3 * jj + 1];
        out[ob + col + 3 * jj + 2] = a3[jj] * inv_sqrt_c + sc[ob + col + 3 * jj + 2];
    }
}

extern "C" void kernel_launch(void* const* d_in, const int* in_sizes, int n_in,
                              void* d_out, int out_size, void* d_ws, size_t ws_size,
                              hipStream_t stream) {
    const float* x     = (const float*)d_in[0];
    const float* y     = (const float*)d_in[1];
    const float* sc    = (const float*)d_in[2];
    const float* u3_l0 = (const float*)d_in[3];
    const float* u2_l0 = (const float*)d_in[4];
    const float* u1_l0 = (const float*)d_in[5];
    const float* w3_l0 = (const float*)d_in[6];
    const float* w2_l0 = (const float*)d_in[7];
    const float* w1_l0 = (const float*)d_in[8];
    const float* u3_l1 = (const float*)d_in[9];
    const float* u2_l1 = (const float*)d_in[10];
    const float* u1_l1 = (const float*)d_in[11];
    const float* w3_l1 = (const float*)d_in[12];
    const float* w2_l1 = (const float*)d_in[13];
    const float* w1_l1 = (const float*)d_in[14];
    const float* lw0   = (const float*)d_in[15];
    const float* lw1   = (const float*)d_in[16];
    float* out = (float*)d_out;

    // Workspace layout (floats): us3 | us2 | us1 | fbuf (float4-aligned)
    float* us3  = (float*)d_ws;
    float* us2  = us3 + US3_FLOATS;
    float* us1  = us2 + US2_FLOATS;
    float4* fbuf = (float4*)(us1 + US1_FLOATS);  // 3252*4 B offset, 16B-aligned

    build_sym_kernel<<<13, 256, 0, stream>>>(
        u3_l0, u2_l0, u1_l0, u3_l1, u2_l1, u1_l1, us3, us2, us1);
    contract_kernel<<<N_NODES / 2, 256, 0, stream>>>(
        x, y, us3, us2, us1,
        w3_l0, w2_l0, w1_l0, w3_l1, w2_l1, w1_l1,
        fbuf);
    linear_kernel<<<N_NODES / 8, 256, 0, stream>>>(fbuf, lw0, lw1, sc, out);
}

// Round 7
// 163.699 us; speedup vs baseline: 4.8839x; 4.8839x over previous
//
#include <hip/hip_runtime.h>

// Problem constants (from reference)
#define N_NODES 2048
#define C_CH    128
#define NIRR    9
#define E_EL    10
// dslot mapping: 0 -> l0 (d=0), 1..3 -> l1 (d=0..2)

// Symmetrized coupling tables (tiny, wave-uniform, scalar-loaded):
//   us3: [s3(165 triples p<=q<=i)][16 = ds*4+k]
//   us2: [s2(45 pairs p<=q)][12 = ds*3+k]
//   us1: [p(9)][8 = ds*2+k]
#define NS3 165
#define NS2 45
#define US3_FLOATS (NS3 * 16)   // 2640
#define US2_FLOATS (NS2 * 12)   //  540
#define US1_FLOATS (9 * 8)      //   72

// Symmetrize u3/u2/u1 over index-permutation orbits (monomial x_p x_q x_i is
// symmetric, so only sorted index tuples matter). Output is 3252 floats total.
__global__ __launch_bounds__(256) void build_sym_kernel(
    const float* __restrict__ u3_l0, const float* __restrict__ u2_l0, const float* __restrict__ u1_l0,
    const float* __restrict__ u3_l1, const float* __restrict__ u2_l1, const float* __restrict__ u1_l1,
    float* __restrict__ us3, float* __restrict__ us2, float* __restrict__ us1)
{
    int t = blockIdx.x * 256 + threadIdx.x;
    if (t < US3_FLOATS) {
        int s = t >> 4, dk = t & 15, ds = dk >> 2, k = dk & 3;
        int pp = 0, qq = 0, ii = 0, cntr = 0;
        for (int p = 0; p < 9; p++)
            for (int q = p; q < 9; q++)
                for (int i = q; i < 9; i++) {
                    if (cntr == s) { pp = p; qq = q; ii = i; }
                    cntr++;
                }
        const float* u = (ds == 0) ? u3_l0 : (u3_l1 + (ds - 1) * 2916);
        int perm[6][3] = {{pp,qq,ii},{pp,ii,qq},{qq,pp,ii},{qq,ii,pp},{ii,pp,qq},{ii,qq,pp}};
        float acc = 0.f;
        #pragma unroll
        for (int j = 0; j < 6; j++)
            acc += u[((perm[j][0] * 9 + perm[j][1]) * 9 + perm[j][2]) * 4 + k];
        float mult = (pp == qq && qq == ii) ? 6.f : ((pp == qq || qq == ii) ? 2.f : 1.f);
        us3[t] = acc / mult;
    } else if (t < US3_FLOATS + US2_FLOATS) {
        int t2 = t - US3_FLOATS;
        int s = t2 / 12, dk = t2 % 12, ds = dk / 3, k = dk % 3;
        int pp = 0, qq = 0, cntr = 0;
        for (int p = 0; p < 9; p++)
            for (int q = p; q < 9; q++) {
                if (cntr == s) { pp = p; qq = q; }
                cntr++;
            }
        const float* u = (ds == 0) ? u2_l0 : (u2_l1 + (ds - 1) * 243);
        float acc = u[(pp * 9 + qq) * 3 + k] + u[(qq * 9 + pp) * 3 + k];
        us2[t2] = (pp == qq) ? acc * 0.5f : acc;
    } else if (t < US3_FLOATS + US2_FLOATS + US1_FLOATS) {
        int t1 = t - US3_FLOATS - US2_FLOATS;
        int p = t1 >> 3, dk = t1 & 7, ds = dk >> 1, k = dk & 1;
        const float* u = (ds == 0) ? u1_l0 : (u1_l1 + (ds - 1) * 18);
        us1[t1] = u[p * 2 + k];
    }
}

// Fused contraction + o3.Linear + skip. grid = 1024 blocks exactly.
// Block = 2 nodes x 128 c; 1 node/thread. Element id inline from one-hot
// (wave-uniform -> readfirstlane to SGPR). Table entries wave-uniform with
// compile-time offsets -> scalar s_load into SGPRs; each FMA is
// v_fmac vG, sU, vX. f[4] staged in LDS (4 KB), one barrier, then each
// thread computes its 4 output columns and writes out directly.
// NOTE: needs >=128 VGPR budget; launch_bounds min-waves must stay <=4
// (R5's (256,8) capped VGPRs at 64 -> scratch spill -> 14x regression).
__global__ __launch_bounds__(256, 4) void fused_kernel(
    const float* __restrict__ x, const float* __restrict__ y,
    const float* __restrict__ us3, const float* __restrict__ us2, const float* __restrict__ us1,
    const float* __restrict__ w3_l0, const float* __restrict__ w2_l0, const float* __restrict__ w1_l0,
    const float* __restrict__ w3_l1, const float* __restrict__ w2_l1, const float* __restrict__ w1_l1,
    const float* __restrict__ lw0, const float* __restrict__ lw1,
    const float* __restrict__ sc, float* __restrict__ out)
{
    __shared__ float fs[4][2][132];  // [m][sub][c], stride 132 for alignment
    int tid = threadIdx.x;
    int c = tid & 127;
    int sub = tid >> 7;
    int b = blockIdx.x * 2 + sub;

    int e = 0;
    #pragma unroll
    for (int k = 1; k < E_EL; k++)
        if (y[b * E_EL + k] > 0.5f) e = k;
    e = __builtin_amdgcn_readfirstlane(e);

    float xv[9];
    {
        const float* xp = x + ((size_t)b * C_CH + c) * NIRR;
        #pragma unroll
        for (int i = 0; i < 9; i++) xv[i] = xp[i];
    }

    float G3[16], G2[12], G1[8];
    #pragma unroll
    for (int t = 0; t < 16; t++) G3[t] = 0.f;
    #pragma unroll
    for (int t = 0; t < 12; t++) G2[t] = 0.f;
    #pragma unroll
    for (int t = 0; t < 8; t++) G1[t] = 0.f;

    int s3 = 0, s2 = 0;
    #pragma unroll
    for (int p = 0; p < 9; p++) {
        float xp = xv[p];
        #pragma unroll
        for (int k = 0; k < 8; k++) G1[k] += us1[p * 8 + k] * xp;
        #pragma unroll
        for (int q = p; q < 9; q++) {
            float pq = xp * xv[q];
            #pragma unroll
            for (int k = 0; k < 12; k++) G2[k] += us2[s2 * 12 + k] * pq;
            s2++;
            #pragma unroll
            for (int i = q; i < 9; i++) {
                float X = pq * xv[i];
                #pragma unroll
                for (int k = 0; k < 16; k++) G3[k] += us3[s3 * 16 + k] * X;
                s3++;
            }
        }
    }

    // element weights (lane c): w3 (E,4,C), w2 (E,3,C), w1 (E,2,C)
    {
        float acc = 0.f;
        #pragma unroll
        for (int k = 0; k < 4; k++) acc += w3_l0[(e * 4 + k) * 128 + c] * G3[k];
        #pragma unroll
        for (int k = 0; k < 3; k++) acc += w2_l0[(e * 3 + k) * 128 + c] * G2[k];
        #pragma unroll
        for (int k = 0; k < 2; k++) acc += w1_l0[(e * 2 + k) * 128 + c] * G1[k];
        fs[0][sub][c] = acc;
    }
    {
        float w31[4], w21[3], w11[2];
        #pragma unroll
        for (int k = 0; k < 4; k++) w31[k] = w3_l1[(e * 4 + k) * 128 + c];
        #pragma unroll
        for (int k = 0; k < 3; k++) w21[k] = w2_l1[(e * 3 + k) * 128 + c];
        #pragma unroll
        for (int k = 0; k < 2; k++) w11[k] = w1_l1[(e * 2 + k) * 128 + c];
        #pragma unroll
        for (int ds = 1; ds < 4; ds++) {
            float acc = 0.f;
            #pragma unroll
            for (int k = 0; k < 4; k++) acc += w31[k] * G3[ds * 4 + k];
            #pragma unroll
            for (int k = 0; k < 3; k++) acc += w21[k] * G2[ds * 3 + k];
            #pragma unroll
            for (int k = 0; k < 2; k++) acc += w11[k] * G1[ds * 2 + k];
            fs[ds][sub][c] = acc;
        }
    }
    __syncthreads();

    // o3.Linear: thread (sub, j=c) computes out cols for node b.
    // fs reads are wave-uniform broadcasts (float4 over i); lw reads coalesced.
    float a0 = 0.f, a1 = 0.f, a2 = 0.f, a3 = 0.f;
    #pragma unroll 8
    for (int ib = 0; ib < 32; ib++) {
        float4 f0 = *(const float4*)&fs[0][sub][4 * ib];
        float4 f1 = *(const float4*)&fs[1][sub][4 * ib];
        float4 f2 = *(const float4*)&fs[2][sub][4 * ib];
        float4 f3 = *(const float4*)&fs[3][sub][4 * ib];
        int i0 = 4 * ib;
        float w0a = lw0[(i0 + 0) * 128 + c], w1a = lw1[(i0 + 0) * 128 + c];
        float w0b = lw0[(i0 + 1) * 128 + c], w1b = lw1[(i0 + 1) * 128 + c];
        float w0c = lw0[(i0 + 2) * 128 + c], w1c = lw1[(i0 + 2) * 128 + c];
        float w0d = lw0[(i0 + 3) * 128 + c], w1d = lw1[(i0 + 3) * 128 + c];
        a0 += f0.x * w0a + f0.y * w0b + f0.z * w0c + f0.w * w0d;
        a1 += f1.x * w1a + f1.y * w1b + f1.z * w1c + f1.w * w1d;
        a2 += f2.x * w1a + f2.y * w1b + f2.z * w1c + f2.w * w1d;
        a3 += f3.x * w1a + f3.y * w1b + f3.z * w1c + f3.w * w1d;
    }

    const float inv_sqrt_c = 0.08838834764831845f;  // 1/sqrt(128)
    size_t ob = (size_t)b * 512;
    out[ob + c] = a0 * inv_sqrt_c + sc[ob + c];
    int col = 128 + 3 * c;
    out[ob + col + 0] = a1 * inv_sqrt_c + sc[ob + col + 0];
    out[ob + col + 1] = a2 * inv_sqrt_c + sc[ob + col + 1];
    out[ob + col + 2] = a3 * inv_sqrt_c + sc[ob + col + 2];
}

extern "C" void kernel_launch(void* const* d_in, const int* in_sizes, int n_in,
                              void* d_out, int out_size, void* d_ws, size_t ws_size,
                              hipStream_t stream) {
    const float* x     = (const float*)d_in[0];
    const float* y     = (const float*)d_in[1];
    const float* sc    = (const float*)d_in[2];
    const float* u3_l0 = (const float*)d_in[3];
    const float* u2_l0 = (const float*)d_in[4];
    const float* u1_l0 = (const float*)d_in[5];
    const float* w3_l0 = (const float*)d_in[6];
    const float* w2_l0 = (const float*)d_in[7];
    const float* w1_l0 = (const float*)d_in[8];
    const float* u3_l1 = (const float*)d_in[9];
    const float* u2_l1 = (const float*)d_in[10];
    const float* u1_l1 = (const float*)d_in[11];
    const float* w3_l1 = (const float*)d_in[12];
    const float* w2_l1 = (const float*)d_in[13];
    const float* w1_l1 = (const float*)d_in[14];
    const float* lw0   = (const float*)d_in[15];
    const float* lw1   = (const float*)d_in[16];
    float* out = (float*)d_out;

    // Workspace layout (floats): us3 | us2 | us1
    float* us3 = (float*)d_ws;
    float* us2 = us3 + US3_FLOATS;
    float* us1 = us2 + US2_FLOATS;

    build_sym_kernel<<<13, 256, 0, stream>>>(
        u3_l0, u2_l0, u1_l0, u3_l1, u2_l1, u1_l1, us3, us2, us1);
    fused_kernel<<<N_NODES / 2, 256, 0, stream>>>(
        x, y, us3, us2, us1,
        w3_l0, w2_l0, w1_l0, w3_l1, w2_l1, w1_l1,
        lw0, lw1, sc, out);
}

// Round 8
// 134.384 us; speedup vs baseline: 5.9493x; 1.2182x over previous
//
#include <hip/hip_runtime.h>

// Problem constants (from reference)
#define N_NODES 2048
#define C_CH    128
#define NIRR    9
#define E_EL    10
// dslot mapping: 0 -> l0 (d=0), 1..3 -> l1 (d=0..2)

// Symmetrized coupling tables, role-major so each wave (one role r = ds)
// scalar-loads a contiguous slice:
//   us3: [r(4)][s3(165)][k(4)]   = 2640 floats
//   us2: [r(4)][s2(45)][k(3)]    =  540
//   us1: [r(4)][p(9)][k(2)]      =   72
#define NS3 165
#define NS2 45
#define US3_FLOATS (NS3 * 16)   // 2640
#define US2_FLOATS (NS2 * 12)   //  540
#define US1_FLOATS (9 * 8)      //   72

// Symmetrize u3/u2/u1 over index-permutation orbits (monomial x_p x_q x_i is
// symmetric, so only sorted index tuples matter). 3252 floats total.
__global__ __launch_bounds__(256) void build_sym_kernel(
    const float* __restrict__ u3_l0, const float* __restrict__ u2_l0, const float* __restrict__ u1_l0,
    const float* __restrict__ u3_l1, const float* __restrict__ u2_l1, const float* __restrict__ u1_l1,
    float* __restrict__ us3, float* __restrict__ us2, float* __restrict__ us1)
{
    int t = blockIdx.x * 256 + threadIdx.x;
    if (t < US3_FLOATS) {
        int s = t >> 4, dk = t & 15, ds = dk >> 2, k = dk & 3;
        int pp = 0, qq = 0, ii = 0, cntr = 0;
        for (int p = 0; p < 9; p++)
            for (int q = p; q < 9; q++)
                for (int i = q; i < 9; i++) {
                    if (cntr == s) { pp = p; qq = q; ii = i; }
                    cntr++;
                }
        const float* u = (ds == 0) ? u3_l0 : (u3_l1 + (ds - 1) * 2916);
        int perm[6][3] = {{pp,qq,ii},{pp,ii,qq},{qq,pp,ii},{qq,ii,pp},{ii,pp,qq},{ii,qq,pp}};
        float acc = 0.f;
        #pragma unroll
        for (int j = 0; j < 6; j++)
            acc += u[((perm[j][0] * 9 + perm[j][1]) * 9 + perm[j][2]) * 4 + k];
        float mult = (pp == qq && qq == ii) ? 6.f : ((pp == qq || qq == ii) ? 2.f : 1.f);
        us3[ds * (NS3 * 4) + s * 4 + k] = acc / mult;
    } else if (t < US3_FLOATS + US2_FLOATS) {
        int t2 = t - US3_FLOATS;
        int s = t2 / 12, dk = t2 % 12, ds = dk / 3, k = dk % 3;
        int pp = 0, qq = 0, cntr = 0;
        for (int p = 0; p < 9; p++)
            for (int q = p; q < 9; q++) {
                if (cntr == s) { pp = p; qq = q; }
                cntr++;
            }
        const float* u = (ds == 0) ? u2_l0 : (u2_l1 + (ds - 1) * 243);
        float acc = u[(pp * 9 + qq) * 3 + k] + u[(qq * 9 + pp) * 3 + k];
        us2[ds * (NS2 * 3) + s * 3 + k] = (pp == qq) ? acc * 0.5f : acc;
    } else if (t < US3_FLOATS + US2_FLOATS + US1_FLOATS) {
        int t1 = t - US3_FLOATS - US2_FLOATS;
        int p = t1 >> 3, dk = t1 & 7, ds = dk >> 1, k = dk & 1;
        const float* u = (ds == 0) ? u1_l0 : (u1_l1 + (ds - 1) * 18);
        us1[ds * 18 + p * 2 + k] = u[p * 2 + k];
    }
}

// Fused contraction + o3.Linear + skip. One node per block.
// Block = 512 = 128 c x 4 roles; role r computes dslot r only (9 accumulators,
// ~1/4 the FMA chain of R6) -> 16384 waves total (4x R6's parallelism).
// r is wave-uniform (forced to SGPR via readfirstlane) so table reads stay
// scalar s_load from contiguous per-role slices.
// NOTE: needs >=100 VGPR headroom; never bound min-waves above 4 here
// (R5's (256,8) capped VGPRs at 64 with 45+ live values -> spill -> 14x).
__global__ __launch_bounds__(512, 4) void fused_kernel(
    const float* __restrict__ x, const float* __restrict__ y,
    const float* __restrict__ us3, const float* __restrict__ us2, const float* __restrict__ us1,
    const float* __restrict__ w3_l0, const float* __restrict__ w2_l0, const float* __restrict__ w1_l0,
    const float* __restrict__ w3_l1, const float* __restrict__ w2_l1, const float* __restrict__ w1_l1,
    const float* __restrict__ lw0, const float* __restrict__ lw1,
    const float* __restrict__ sc, float* __restrict__ out)
{
    __shared__ float fs[4][132];   // [dslot][c], stride 132 keeps float4 rows aligned
    int tid = threadIdx.x;
    int c = tid & 127;
    int r = __builtin_amdgcn_readfirstlane(tid >> 7);   // role == dslot, wave-uniform
    int b = blockIdx.x;

    int e = 0;
    #pragma unroll
    for (int k = 1; k < E_EL; k++)
        if (y[b * E_EL + k] > 0.5f) e = k;
    e = __builtin_amdgcn_readfirstlane(e);

    float xv[9];
    {
        const float* xp = x + ((size_t)b * C_CH + c) * NIRR;
        #pragma unroll
        for (int i = 0; i < 9; i++) xv[i] = xp[i];
    }

    const float* t3 = us3 + r * (NS3 * 4);
    const float* t2 = us2 + r * (NS2 * 3);
    const float* t1 = us1 + r * 18;

    float G3[4] = {0.f, 0.f, 0.f, 0.f};
    float G2[3] = {0.f, 0.f, 0.f};
    float G1[2] = {0.f, 0.f};

    int s3 = 0, s2 = 0;
    #pragma unroll
    for (int p = 0; p < 9; p++) {
        float xp = xv[p];
        G1[0] += t1[p * 2 + 0] * xp;
        G1[1] += t1[p * 2 + 1] * xp;
        #pragma unroll
        for (int q = p; q < 9; q++) {
            float pq = xp * xv[q];
            G2[0] += t2[s2 * 3 + 0] * pq;
            G2[1] += t2[s2 * 3 + 1] * pq;
            G2[2] += t2[s2 * 3 + 2] * pq;
            s2++;
            #pragma unroll
            for (int i = q; i < 9; i++) {
                float X = pq * xv[i];
                G3[0] += t3[s3 * 4 + 0] * X;
                G3[1] += t3[s3 * 4 + 1] * X;
                G3[2] += t3[s3 * 4 + 2] * X;
                G3[3] += t3[s3 * 4 + 3] * X;
                s3++;
            }
        }
    }

    // element weights (lane c): w3 (E,4,C), w2 (E,3,C), w1 (E,2,C)
    float acc = 0.f;
    if (r == 0) {
        #pragma unroll
        for (int k = 0; k < 4; k++) acc += w3_l0[(e * 4 + k) * 128 + c] * G3[k];
        #pragma unroll
        for (int k = 0; k < 3; k++) acc += w2_l0[(e * 3 + k) * 128 + c] * G2[k];
        #pragma unroll
        for (int k = 0; k < 2; k++) acc += w1_l0[(e * 2 + k) * 128 + c] * G1[k];
    } else {
        #pragma unroll
        for (int k = 0; k < 4; k++) acc += w3_l1[(e * 4 + k) * 128 + c] * G3[k];
        #pragma unroll
        for (int k = 0; k < 3; k++) acc += w2_l1[(e * 3 + k) * 128 + c] * G2[k];
        #pragma unroll
        for (int k = 0; k < 2; k++) acc += w1_l1[(e * 2 + k) * 128 + c] * G1[k];
    }
    fs[r][c] = acc;
    __syncthreads();

    // o3.Linear: 512 threads <-> 512 output columns of this node.
    //   tid < 128: col = tid (l0 block, weights lw0, fs[0])
    //   else: u = tid-128, m = u>>7, j = u&127 -> col = 128 + 3j + m,
    //         weights lw1 (coalesced in j), fs[1+m] (wave-uniform broadcast)
    int sel, j, col;
    const float* W;
    if (tid < 128) { sel = 0; j = tid; col = tid; W = lw0; }
    else {
        int u = tid - 128;
        int m = u >> 7;
        j = u & 127;
        sel = 1 + m;
        col = 128 + 3 * j + m;
        W = lw1;
    }
    sel = __builtin_amdgcn_readfirstlane(sel);

    float a = 0.f;
    #pragma unroll 8
    for (int ib = 0; ib < 32; ib++) {
        float4 f = *(const float4*)&fs[sel][4 * ib];
        int i0 = 4 * ib;
        a += f.x * W[(i0 + 0) * 128 + j];
        a += f.y * W[(i0 + 1) * 128 + j];
        a += f.z * W[(i0 + 2) * 128 + j];
        a += f.w * W[(i0 + 3) * 128 + j];
    }

    const float inv_sqrt_c = 0.08838834764831845f;  // 1/sqrt(128)
    size_t oi = (size_t)b * 512 + col;
    out[oi] = a * inv_sqrt_c + sc[oi];
}

extern "C" void kernel_launch(void* const* d_in, const int* in_sizes, int n_in,
                              void* d_out, int out_size, void* d_ws, size_t ws_size,
                              hipStream_t stream) {
    const float* x     = (const float*)d_in[0];
    const float* y     = (const float*)d_in[1];
    const float* sc    = (const float*)d_in[2];
    const float* u3_l0 = (const float*)d_in[3];
    const float* u2_l0 = (const float*)d_in[4];
    const float* u1_l0 = (const float*)d_in[5];
    const float* w3_l0 = (const float*)d_in[6];
    const float* w2_l0 = (const float*)d_in[7];
    const float* w1_l0 = (const float*)d_in[8];
    const float* u3_l1 = (const float*)d_in[9];
    const float* u2_l1 = (const float*)d_in[10];
    const float* u1_l1 = (const float*)d_in[11];
    const float* w3_l1 = (const float*)d_in[12];
    const float* w2_l1 = (const float*)d_in[13];
    const float* w1_l1 = (const float*)d_in[14];
    const float* lw0   = (const float*)d_in[15];
    const float* lw1   = (const float*)d_in[16];
    float* out = (float*)d_out;

    // Workspace layout (floats): us3 | us2 | us1
    float* us3 = (float*)d_ws;
    float* us2 = us3 + US3_FLOATS;
    float* us1 = us2 + US2_FLOATS;

    build_sym_kernel<<<13, 256, 0, stream>>>(
        u3_l0, u2_l0, u1_l0, u3_l1, u2_l1, u1_l1, us3, us2, us1);
    fused_kernel<<<N_NODES, 512, 0, stream>>>(
        x, y, us3, us2, us1,
        w3_l0, w2_l0, w1_l0, w3_l1, w2_l1, w1_l1,
        lw0, lw1, sc, out);
}